// Round 2
// baseline (432.053 us; speedup 1.0000x reference)
//
#include <hip/hip_runtime.h>
#include <math.h>

// Problem constants (from reference setup_inputs)
#define BATCH 8
#define CIN 512
#define H 128
#define W 128
#define COUT 3
#define CHUNKS 32
#define CH (CIN / CHUNKS)          // 16 channels per block
#define R 8                        // output rows per wave
#define NROWS (R + 2)              // input rows touched per wave (halo)
#define WAVES 4
#define BLOCK_ROWS (R * WAVES)     // 32
#define TILES_Y (H / BLOCK_ROWS)   // 4

// Compute one input channel's contribution. cur[r] holds input row (yb-1+r),
// cols (2*lane, 2*lane+1). Boundary-row masking (m0/m9) applied here.
// wp points at this channel's taps for co=0; co stride is CIN*9.
__device__ __forceinline__ void compute_ch(
    const float2 (&cur)[NROWS], const float* __restrict__ wp,
    float (&acc)[R][2][3], int lane, float m0, float m9)
{
    float wv[27];
#pragma unroll
    for (int co = 0; co < 3; co++)
#pragma unroll
        for (int k = 0; k < 9; k++)
            wv[co * 9 + k] = wp[co * (CIN * 9) + k];   // wave-uniform -> s_load

    // sliding 3-row window: lw = col x-1, ax/ay = cols x0/x1, rw = col x+2
    float lw[3], ax[3], ay[3], rw[3];
#pragma unroll
    for (int rr = 0; rr < NROWS; rr++) {
        // fill slot for row rr (first two rows fill slots 0,1 before FMA use)
        const int s = rr % 3;
        float vx = cur[rr].x, vy = cur[rr].y;
        if (rr == 0)         { vx *= m0; vy *= m0; }
        if (rr == NROWS - 1) { vx *= m9; vy *= m9; }
        float l = __shfl_up(vy, 1);
        float r_ = __shfl_down(vx, 1);
        lw[s] = (lane == 0)  ? 0.f : l;
        rw[s] = (lane == 63) ? 0.f : r_;
        ax[s] = vx; ay[s] = vy;

        if (rr >= 2) {
            const int p  = rr - 2;
            const int s0 = p % 3, s1 = (p + 1) % 3, s2 = (p + 2) % 3;
#pragma unroll
            for (int co = 0; co < 3; co++) {
                const float* w = &wv[co * 9];
                float a0 = acc[p][0][co], a1 = acc[p][1][co];
                a0 += lw[s0] * w[0] + ax[s0] * w[1] + ay[s0] * w[2];
                a1 += ax[s0] * w[0] + ay[s0] * w[1] + rw[s0] * w[2];
                a0 += lw[s1] * w[3] + ax[s1] * w[4] + ay[s1] * w[5];
                a1 += ax[s1] * w[3] + ay[s1] * w[4] + rw[s1] * w[5];
                a0 += lw[s2] * w[6] + ax[s2] * w[7] + ay[s2] * w[8];
                a1 += ax[s2] * w[6] + ay[s2] * w[7] + rw[s2] * w[8];
                acc[p][0][co] = a0; acc[p][1][co] = a1;
            }
        }
    }
}

__device__ __forceinline__ void prefetch_ch(
    float2 (&buf)[NROWS], const float* __restrict__ chan,
    const int (&goff)[NROWS], int x0)
{
#pragma unroll
    for (int r = 0; r < NROWS; r++)
        buf[r] = *(const float2*)(chan + goff[r] + x0);
}

__global__ __launch_bounds__(256) void torgb_conv(
    const float* __restrict__ in, const float* __restrict__ skip,
    const float* __restrict__ weight, const float* __restrict__ bias,
    float* __restrict__ out)
{
    const int bx    = blockIdx.x;
    const int tile  = bx & (TILES_Y - 1);
    const int b     = (bx >> 2) & (BATCH - 1);
    const int chunk = bx >> 5;                 // 0..31
    const int ci0   = chunk * CH;

    const int tid  = threadIdx.x;
    const int lane = tid & 63;
    const int wave = tid >> 6;
    const int yb   = tile * BLOCK_ROWS + wave * R;   // first output row of this wave
    const int x0   = 2 * lane;                       // first of 2 owned columns

    // row offsets (clamped) + boundary masks — wave-uniform
    int goff[NROWS];
#pragma unroll
    for (int r = 0; r < NROWS; r++) {
        int g = yb - 1 + r;
        int gc = g < 0 ? 0 : (g > H - 1 ? H - 1 : g);
        goff[r] = gc * W;
    }
    const float m0 = (yb >= 1) ? 1.f : 0.f;
    const float m9 = (yb + R <= H - 1) ? 1.f : 0.f;

    float acc[R][2][3];
#pragma unroll
    for (int p = 0; p < R; p++)
#pragma unroll
        for (int q = 0; q < 2; q++)
#pragma unroll
            for (int c = 0; c < 3; c++) acc[p][q][c] = 0.f;

    const float* chan0 = in + ((size_t)b * CIN + ci0) * H * W;
    const float* wbase = weight + (size_t)ci0 * 9;

    float2 bufA[NROWS], bufB[NROWS];
    prefetch_ch(bufA, chan0, goff, x0);

#pragma unroll 2
    for (int ci = 0; ci < CH; ci += 2) {
        prefetch_ch(bufB, chan0 + (size_t)(ci + 1) * H * W, goff, x0);
        compute_ch(bufA, wbase + (size_t)ci * 9, acc, lane, m0, m9);
        if (ci + 2 < CH)
            prefetch_ch(bufA, chan0 + (size_t)(ci + 2) * H * W, goff, x0);
        compute_ch(bufB, wbase + (size_t)(ci + 1) * 9, acc, lane, m0, m9);
    }

    // ---------------- epilogue ----------------
    const float scale = 1.0f / sqrtf((float)(CIN * 9));
    float* outb = out + (size_t)b * COUT * H * W;

    // horizontal skip-upsample taps per owned column (separable [.25 .75 .75 .25])
    int j0[2], j1[2]; float wh0[2], wh1[2]; bool j0ok[2], j1ok[2];
#pragma unroll
    for (int q = 0; q < 2; q++) {
        int x = x0 + q;
        if ((x & 1) == 0) { j0[q] = x >> 1;       wh0[q] = 0.75f; j1[q] = (x >> 1) - 1; wh1[q] = 0.25f; }
        else              { j0[q] = (x + 1) >> 1; wh0[q] = 0.25f; j1[q] = (x - 1) >> 1; wh1[q] = 0.75f; }
        j0ok[q] = (j0[q] >= 0 && j0[q] < 64);
        j1ok[q] = (j1[q] >= 0 && j1[q] < 64);
    }

#pragma unroll
    for (int p = 0; p < R; p++) {
        int y = yb + p;
        int i0, i1; float wv0, wv1;
        if ((y & 1) == 0) { i0 = y >> 1;       wv0 = 0.75f; i1 = (y >> 1) - 1; wv1 = 0.25f; }
        else              { i0 = (y + 1) >> 1; wv0 = 0.25f; i1 = (y - 1) >> 1; wv1 = 0.75f; }
        const bool i0ok = (i0 >= 0 && i0 < 64), i1ok = (i1 >= 0 && i1 < 64);
#pragma unroll
        for (int q = 0; q < 2; q++) {
            int x = x0 + q;
#pragma unroll
            for (int co = 0; co < 3; co++) {
                float v = acc[p][q][co] * scale;
                if (chunk == 0) {
                    const float* sk = skip + (size_t)(b * COUT + co) * 64 * 64;
                    float s00 = (i0ok && j0ok[q]) ? sk[i0 * 64 + j0[q]] : 0.f;
                    float s01 = (i0ok && j1ok[q]) ? sk[i0 * 64 + j1[q]] : 0.f;
                    float s10 = (i1ok && j0ok[q]) ? sk[i1 * 64 + j0[q]] : 0.f;
                    float s11 = (i1ok && j1ok[q]) ? sk[i1 * 64 + j1[q]] : 0.f;
                    v += bias[co] + wv0 * (wh0[q] * s00 + wh1[q] * s01)
                                  + wv1 * (wh0[q] * s10 + wh1[q] * s11);
                }
                atomicAdd(&outb[(size_t)co * H * W + y * W + x], v);
            }
        }
    }
}

extern "C" void kernel_launch(void* const* d_in, const int* in_sizes, int n_in,
                              void* d_out, int out_size, void* d_ws, size_t ws_size,
                              hipStream_t stream) {
    const float* in     = (const float*)d_in[0];
    const float* skip   = (const float*)d_in[1];
    const float* weight = (const float*)d_in[2];
    const float* bias   = (const float*)d_in[3];
    float* out = (float*)d_out;

    hipMemsetAsync(out, 0, (size_t)out_size * sizeof(float), stream);
    dim3 grid(CHUNKS * BATCH * TILES_Y);  // 1024 blocks
    torgb_conv<<<grid, 256, 0, stream>>>(in, skip, weight, bias, out);
}